// Round 5
// baseline (1296.766 us; speedup 1.0000x reference)
//
#include <hip/hip_runtime.h>
#include <math.h>

// LaplacianLoss: out[b] = vertex_weight * ||L @ x[b]||_F * NV
// Round-5: round-4 pipeline with the scratch-spill root cause fixed.
// Rounds 3/4 spilled acc to scratch (VGPR=84, 1.75-2.25 GB scratch traffic):
// the epilogue's *(float4*)&acc[...] cast of an unaligned stack array blocked
// SROA promotion. This version never takes the address of ANY local array:
//  - acc: constant-indexed scalars only; epilogue uses make_float4
//  - Lc/Ln: float4 by component, unpacked via constant-init scalar arrays
//  - xv: three float4 loads unpacked the same way
// Structure (unchanged from r4): 1 barrier/tile, double-buffered x tile via
// global_load_lds width=16, L float4 prefetch issued before compute, C split
// per j-half (plain stores), single-block shuffle-reduce finalizer.

#define NVERT 10000
#define TJ 256
#define TPJG 20          // tiles per j-half
#define RPW 4            // rows per wave
#define RPB 16           // rows per block
#define NRG 625
#define GRID1 (NRG * 2)

typedef const __attribute__((address_space(1))) void* as1_cptr;
typedef __attribute__((address_space(3))) void* as3_ptr;

__device__ __forceinline__ void lds_load16(void* lds, const void* g) {
  __builtin_amdgcn_global_load_lds((as1_cptr)g, (as3_ptr)lds, 16, 0, 0);
}

__global__ __launch_bounds__(256, 3) void lap_main(
    const float* __restrict__ x, const float* __restrict__ L,
    float* __restrict__ C) {
  // two x-tile buffers of 1536 float4 (49152 B -> 3 blocks/CU);
  // epilogue reuses floats [0..6399].
  __shared__ __align__(16) float smem[12288];

  const int tid  = threadIdx.x;
  const int lane = tid & 63;
  const int wave = tid >> 6;
  const int rg   = blockIdx.x >> 1;
  const int jg   = blockIdx.x & 1;
  const int row0 = rg * RPB + wave * RPW;
  const int t0   = jg * TPJG;
  const int b0   = 2 * wave;    // this wave stages batches b0, b0+1

  float acc[RPW][24];
#pragma unroll
  for (int r = 0; r < RPW; ++r)
#pragma unroll
    for (int n = 0; n < 24; ++n) acc[r][n] = 0.f;

  const float4* __restrict__ xg = (const float4*)x;  // [b][2500 f4]
  float4* const smem4 = (float4*)smem;
  const float* const Lbase = L + (long)row0 * NVERT;

  // ---- prologue: DMA-stage tile t0 into buf0; prefetch L(t0) ----
#pragma unroll
  for (int bb = 0; bb < 2; ++bb) {
    const int b = b0 + bb;
#pragma unroll
    for (int r = 0; r < 3; ++r) {
      const int idx = r * 64 + lane;
      lds_load16(&smem4[b * 192 + idx], &xg[b * 7500 + t0 * 192 + idx]);
    }
  }
  float4 Lc[RPW];
  {
    const int c0 = t0 * TJ + 4 * lane;
#pragma unroll
    for (int r = 0; r < RPW; ++r)
      Lc[r] = *(const float4*)(Lbase + r * NVERT + c0);
  }
  __syncthreads();  // drains LDS-DMA + all waves staged

  // ---- main loop: one barrier per tile ----
#pragma unroll 2
  for (int tt = 0; tt < TPJG; ++tt) {
    const int q = tt & 1;
    const int t = t0 + tt;
    const bool last = (tt == TPJG - 1);
    const int jc  = (jg == 1 && tt == TPJG - 1) ? 16 : TJ;  // this tile cols
    const int jcn = (jg == 1 && tt == TPJG - 2) ? 16 : TJ;  // next tile cols

    // phase A: DMA-stage next x tile into the other buffer (no staging VGPRs)
    if (!last) {
#pragma unroll
      for (int bb = 0; bb < 2; ++bb) {
        const int b = b0 + bb;
#pragma unroll
        for (int r = 0; r < 3; ++r) {
          const int idx = r * 64 + lane;
          int gi = (t + 1) * 192 + idx;
          gi = (gi < 7499 ? gi : 7499) + b * 7500;  // clamp: tail-tile safety
          lds_load16(&smem4[(1 - q) * 1536 + b * 192 + idx], &xg[gi]);
        }
      }
    }

    // phase B: prefetch next L tile (HBM ~900cyc; covered by phase C compute)
    float4 Ln[RPW];
#pragma unroll
    for (int r = 0; r < RPW; ++r) Ln[r] = make_float4(0.f, 0.f, 0.f, 0.f);
    if (!last && 4 * lane < jcn) {
      const int cn = (t + 1) * TJ + 4 * lane;
#pragma unroll
      for (int r = 0; r < RPW; ++r)
        Ln[r] = *(const float4*)(Lbase + r * NVERT + cn);
    }

    // phase C: compute all 8 batches on buffer q with prefetched Lc
    if (4 * lane < jc) {
      const float* xs = smem + q * 6144 + 12 * lane;
#pragma unroll
      for (int b = 0; b < 8; ++b) {
        const float4 x0 = *(const float4*)(xs + b * 768);
        const float4 x1 = *(const float4*)(xs + b * 768 + 4);
        const float4 x2 = *(const float4*)(xs + b * 768 + 8);
        const float xf[12] = {x0.x, x0.y, x0.z, x0.w,
                              x1.x, x1.y, x1.z, x1.w,
                              x2.x, x2.y, x2.z, x2.w};
#pragma unroll
        for (int r = 0; r < RPW; ++r) {
          const float Ls[4] = {Lc[r].x, Lc[r].y, Lc[r].z, Lc[r].w};
#pragma unroll
          for (int jj = 0; jj < 4; ++jj) {
            const float s = Ls[jj];
#pragma unroll
            for (int k = 0; k < 3; ++k)
              acc[r][b * 3 + k] += s * xf[jj * 3 + k];
          }
        }
      }
    }

    __syncthreads();  // next buffer fully staged; buf q free for rewrite
#pragma unroll
    for (int r = 0; r < RPW; ++r) Lc[r] = Ln[r];
  }

  // ---- epilogue (once per block): cross-lane sum per (row,n) -> store C ----
  float* const Cs = C + jg * 240000;
  for (int w = 0; w < 4; ++w) {
    __syncthreads();
    if (wave == w) {
#pragma unroll
      for (int r = 0; r < RPW; ++r)
#pragma unroll
        for (int c = 0; c < 6; ++c) {
          const float4 v = make_float4(acc[r][c * 4], acc[r][c * 4 + 1],
                                       acc[r][c * 4 + 2], acc[r][c * 4 + 3]);
          *(float4*)&smem[lane * 100 + r * 24 + c * 4] = v;
        }
    }
    __syncthreads();
    if (tid < 96) {
      float s = 0.f;
#pragma unroll
      for (int l = 0; l < 64; ++l) s += smem[l * 100 + tid];
      const int row = rg * RPB + w * RPW + tid / 24;
      Cs[row * 24 + (tid % 24)] = s;   // plain store: slice fully covered
    }
  }
}

__global__ __launch_bounds__(1024) void lap_reduce(
    const float* __restrict__ C, const float* __restrict__ wv,
    float* __restrict__ out) {
  __shared__ float sS[8];
  const int tid = threadIdx.x;
  if (tid < 8) sS[tid] = 0.f;
  __syncthreads();

  float pb[8] = {0.f, 0.f, 0.f, 0.f, 0.f, 0.f, 0.f, 0.f};
  for (int row = tid; row < NVERT; row += 1024) {
    const float4* r0 = (const float4*)(C + row * 24);
    const float4* r1 = (const float4*)(C + 240000 + row * 24);
#pragma unroll
    for (int c = 0; c < 6; ++c) {
      const float4 a = r0[c], b = r1[c];
      const float v0 = a.x + b.x, v1 = a.y + b.y, v2 = a.z + b.z, v3 = a.w + b.w;
      // element e = 4c+i belongs to batch (4c+i)/3
      const int e = 4 * c;
      pb[(e + 0) / 3] += v0 * v0;
      pb[(e + 1) / 3] += v1 * v1;
      pb[(e + 2) / 3] += v2 * v2;
      pb[(e + 3) / 3] += v3 * v3;
    }
  }
#pragma unroll
  for (int off = 32; off > 0; off >>= 1)
#pragma unroll
    for (int b = 0; b < 8; ++b) pb[b] += __shfl_down(pb[b], off);
  if ((tid & 63) == 0)
#pragma unroll
    for (int b = 0; b < 8; ++b) atomicAdd(&sS[b], pb[b]);
  __syncthreads();
  if (tid < 8) out[tid] = wv[0] * sqrtf(sS[tid]) * (float)NVERT;
}

extern "C" void kernel_launch(void* const* d_in, const int* in_sizes, int n_in,
                              void* d_out, int out_size, void* d_ws, size_t ws_size,
                              hipStream_t stream) {
  const float* x  = (const float*)d_in[0];   // (8, 10000, 3) fp32
  const float* L  = (const float*)d_in[1];   // (10000, 10000) fp32
  const float* wv = (const float*)d_in[2];   // (1,) fp32
  float* out = (float*)d_out;                // (8,) fp32

  float* C = (float*)d_ws;  // [2][10000][24] fp32, fully overwritten each call

  lap_main<<<GRID1, 256, 0, stream>>>(x, L, C);
  lap_reduce<<<1, 1024, 0, stream>>>(C, wv, out);
}

// Round 6
// 650.952 us; speedup vs baseline: 1.9921x; 1.9921x over previous
//
#include <hip/hip_runtime.h>
#include <math.h>

// LaplacianLoss: out[b] = vertex_weight * ||L @ x[b]||_F * NV
// Round-6: round-5 code with ONE change: __launch_bounds__(256) -- no
// min-waves arg. Evidence: r3/r4/r5 (three different code shapes, all with
// __launch_bounds__(256,3)) produced the IDENTICAL VGPR_Count=84 plus ~2GB
// scratch traffic; r1 with plain __launch_bounds__(256) got VGPR=148 and no
// spill. 84 = granule(512/6): the min-waves arg caps the allocator at 6
// waves/EU (2x the documented formula) -- an externally imposed cap, not a
// code-shape issue. Dropping it lets the allocator take the ~160 VGPRs the
// pipeline actually needs (3 waves/EU, matching the 48KB-LDS 3-blocks/CU).
//
// Structure (frozen from r5): 1 barrier/tile, double-buffered x tile staged
// via global_load_lds width=16 (zero staging VGPRs), L float4 prefetch
// issued before compute (~900cyc HBM latency covered by 8-batch FMA block),
// C split per j-half (plain stores, no memset/atomics), single-block
// shuffle-reduce finalizer.

#define NVERT 10000
#define TJ 256
#define TPJG 20          // tiles per j-half
#define RPW 4            // rows per wave
#define RPB 16           // rows per block
#define NRG 625
#define GRID1 (NRG * 2)

typedef const __attribute__((address_space(1))) void* as1_cptr;
typedef __attribute__((address_space(3))) void* as3_ptr;

__device__ __forceinline__ void lds_load16(void* lds, const void* g) {
  __builtin_amdgcn_global_load_lds((as1_cptr)g, (as3_ptr)lds, 16, 0, 0);
}

__global__ __launch_bounds__(256) void lap_main(
    const float* __restrict__ x, const float* __restrict__ L,
    float* __restrict__ C) {
  // two x-tile buffers of 1536 float4 (49152 B -> 3 blocks/CU);
  // epilogue reuses floats [0..6399].
  __shared__ __align__(16) float smem[12288];

  const int tid  = threadIdx.x;
  const int lane = tid & 63;
  const int wave = tid >> 6;
  const int rg   = blockIdx.x >> 1;
  const int jg   = blockIdx.x & 1;
  const int row0 = rg * RPB + wave * RPW;
  const int t0   = jg * TPJG;
  const int b0   = 2 * wave;    // this wave stages batches b0, b0+1

  float acc[RPW][24];
#pragma unroll
  for (int r = 0; r < RPW; ++r)
#pragma unroll
    for (int n = 0; n < 24; ++n) acc[r][n] = 0.f;

  const float4* __restrict__ xg = (const float4*)x;  // [b][2500 f4]
  float4* const smem4 = (float4*)smem;
  const float* const Lbase = L + (long)row0 * NVERT;

  // ---- prologue: DMA-stage tile t0 into buf0; prefetch L(t0) ----
#pragma unroll
  for (int bb = 0; bb < 2; ++bb) {
    const int b = b0 + bb;
#pragma unroll
    for (int r = 0; r < 3; ++r) {
      const int idx = r * 64 + lane;
      lds_load16(&smem4[b * 192 + idx], &xg[b * 7500 + t0 * 192 + idx]);
    }
  }
  float4 Lc[RPW];
  {
    const int c0 = t0 * TJ + 4 * lane;
#pragma unroll
    for (int r = 0; r < RPW; ++r)
      Lc[r] = *(const float4*)(Lbase + r * NVERT + c0);
  }
  __syncthreads();  // drains LDS-DMA (vmcnt) + all waves staged

  // ---- main loop: one barrier per tile ----
#pragma unroll 2
  for (int tt = 0; tt < TPJG; ++tt) {
    const int q = tt & 1;
    const int t = t0 + tt;
    const bool last = (tt == TPJG - 1);
    const int jc  = (jg == 1 && tt == TPJG - 1) ? 16 : TJ;  // this tile cols
    const int jcn = (jg == 1 && tt == TPJG - 2) ? 16 : TJ;  // next tile cols

    // phase A: DMA-stage next x tile into the other buffer (no staging VGPRs)
    if (!last) {
#pragma unroll
      for (int bb = 0; bb < 2; ++bb) {
        const int b = b0 + bb;
#pragma unroll
        for (int r = 0; r < 3; ++r) {
          const int idx = r * 64 + lane;
          int gi = (t + 1) * 192 + idx;
          gi = (gi < 7499 ? gi : 7499) + b * 7500;  // clamp: tail-tile safety
          lds_load16(&smem4[(1 - q) * 1536 + b * 192 + idx], &xg[gi]);
        }
      }
    }

    // phase B: prefetch next L tile (HBM ~900cyc; covered by phase C compute)
    float4 Ln[RPW];
#pragma unroll
    for (int r = 0; r < RPW; ++r) Ln[r] = make_float4(0.f, 0.f, 0.f, 0.f);
    if (!last && 4 * lane < jcn) {
      const int cn = (t + 1) * TJ + 4 * lane;
#pragma unroll
      for (int r = 0; r < RPW; ++r)
        Ln[r] = *(const float4*)(Lbase + r * NVERT + cn);
    }

    // phase C: compute all 8 batches on buffer q with prefetched Lc
    if (4 * lane < jc) {
      const float* xs = smem + q * 6144 + 12 * lane;
#pragma unroll
      for (int b = 0; b < 8; ++b) {
        const float4 x0 = *(const float4*)(xs + b * 768);
        const float4 x1 = *(const float4*)(xs + b * 768 + 4);
        const float4 x2 = *(const float4*)(xs + b * 768 + 8);
        const float xf[12] = {x0.x, x0.y, x0.z, x0.w,
                              x1.x, x1.y, x1.z, x1.w,
                              x2.x, x2.y, x2.z, x2.w};
#pragma unroll
        for (int r = 0; r < RPW; ++r) {
          const float Ls[4] = {Lc[r].x, Lc[r].y, Lc[r].z, Lc[r].w};
#pragma unroll
          for (int jj = 0; jj < 4; ++jj) {
            const float s = Ls[jj];
#pragma unroll
            for (int k = 0; k < 3; ++k)
              acc[r][b * 3 + k] += s * xf[jj * 3 + k];
          }
        }
      }
    }

    __syncthreads();  // next buffer fully staged; buf q free for rewrite
#pragma unroll
    for (int r = 0; r < RPW; ++r) Lc[r] = Ln[r];
  }

  // ---- epilogue (once per block): cross-lane sum per (row,n) -> store C ----
  float* const Cs = C + jg * 240000;
  for (int w = 0; w < 4; ++w) {
    __syncthreads();
    if (wave == w) {
#pragma unroll
      for (int r = 0; r < RPW; ++r)
#pragma unroll
        for (int c = 0; c < 6; ++c) {
          const float4 v = make_float4(acc[r][c * 4], acc[r][c * 4 + 1],
                                       acc[r][c * 4 + 2], acc[r][c * 4 + 3]);
          *(float4*)&smem[lane * 100 + r * 24 + c * 4] = v;
        }
    }
    __syncthreads();
    if (tid < 96) {
      float s = 0.f;
#pragma unroll
      for (int l = 0; l < 64; ++l) s += smem[l * 100 + tid];
      const int row = rg * RPB + w * RPW + tid / 24;
      Cs[row * 24 + (tid % 24)] = s;   // plain store: slice fully covered
    }
  }
}

__global__ __launch_bounds__(1024) void lap_reduce(
    const float* __restrict__ C, const float* __restrict__ wv,
    float* __restrict__ out) {
  __shared__ float sS[8];
  const int tid = threadIdx.x;
  if (tid < 8) sS[tid] = 0.f;
  __syncthreads();

  float pb[8] = {0.f, 0.f, 0.f, 0.f, 0.f, 0.f, 0.f, 0.f};
  for (int row = tid; row < NVERT; row += 1024) {
    const float4* r0 = (const float4*)(C + row * 24);
    const float4* r1 = (const float4*)(C + 240000 + row * 24);
#pragma unroll
    for (int c = 0; c < 6; ++c) {
      const float4 a = r0[c], b = r1[c];
      const float v0 = a.x + b.x, v1 = a.y + b.y, v2 = a.z + b.z, v3 = a.w + b.w;
      const int e = 4 * c;  // element e belongs to batch e/3
      pb[(e + 0) / 3] += v0 * v0;
      pb[(e + 1) / 3] += v1 * v1;
      pb[(e + 2) / 3] += v2 * v2;
      pb[(e + 3) / 3] += v3 * v3;
    }
  }
#pragma unroll
  for (int off = 32; off > 0; off >>= 1)
#pragma unroll
    for (int b = 0; b < 8; ++b) pb[b] += __shfl_down(pb[b], off);
  if ((tid & 63) == 0)
#pragma unroll
    for (int b = 0; b < 8; ++b) atomicAdd(&sS[b], pb[b]);
  __syncthreads();
  if (tid < 8) out[tid] = wv[0] * sqrtf(sS[tid]) * (float)NVERT;
}

extern "C" void kernel_launch(void* const* d_in, const int* in_sizes, int n_in,
                              void* d_out, int out_size, void* d_ws, size_t ws_size,
                              hipStream_t stream) {
  const float* x  = (const float*)d_in[0];   // (8, 10000, 3) fp32
  const float* L  = (const float*)d_in[1];   // (10000, 10000) fp32
  const float* wv = (const float*)d_in[2];   // (1,) fp32
  float* out = (float*)d_out;                // (8,) fp32

  float* C = (float*)d_ws;  // [2][10000][24] fp32, fully overwritten each call

  lap_main<<<GRID1, 256, 0, stream>>>(x, L, C);
  lap_reduce<<<1, 1024, 0, stream>>>(C, wv, out);
}